// Round 1
// baseline (40041.873 us; speedup 1.0000x reference)
//
#include <hip/hip_runtime.h>
#include <hip/hip_cooperative_groups.h>

namespace cg = cooperative_groups;

typedef _Float16 f16;
typedef _Float16 f16x4 __attribute__((ext_vector_type(4)));
typedef _Float16 f16x8 __attribute__((ext_vector_type(8)));
typedef float f32x4 __attribute__((ext_vector_type(4)));

#define S_LEN 512
#define BSZ 64
#define ISZ 512
#define HSZ 1024
// GEMM1: M = BSZ*S_LEN = 32768, N = 4096, K = 512

__device__ __forceinline__ float fast_sigmoid(float x) {
  return 1.f / (1.f + __expf(-x));
}
__device__ __forceinline__ float fast_tanh(float x) {
  float t = __expf(-2.f * fabsf(x));          // stable for large |x|
  float r = (1.f - t) / (1.f + t);
  return copysignf(r, x);
}

// ---- setup kernels -------------------------------------------------------
__global__ void k_cvt(const float* __restrict__ src, f16* __restrict__ dst, int n4) {
  int i = blockIdx.x * blockDim.x + threadIdx.x;
  if (i < n4) {
    float4 v = ((const float4*)src)[i];
    f16x4 h = { (f16)v.x, (f16)v.y, (f16)v.z, (f16)v.w };
    ((f16x4*)dst)[i] = h;
  }
}

// pack w_hh rows into per-WG order: packed row rg = wg*16 + (jj*4 + cls)
// <-> source row cls*H + wg*4 + jj   (cls: 0=i,1=f,2=g,3=o)
__global__ void k_pack_whh(const float* __restrict__ whh, f16* __restrict__ wp) {
  int i = blockIdx.x * blockDim.x + threadIdx.x;  // one per 4 elements
  int idx4 = i * 4;
  int k  = idx4 & (HSZ - 1);
  int rg = idx4 >> 10;                 // 0..4095
  int wg = rg >> 4, r = rg & 15;
  int jj = r >> 2, cls = r & 3;
  int srow = cls * HSZ + wg * 4 + jj;
  float4 v = *(const float4*)&whh[(size_t)srow * HSZ + k];
  f16x4 h = { (f16)v.x, (f16)v.y, (f16)v.z, (f16)v.w };
  *(f16x4*)&wp[(size_t)rg * HSZ + k] = h;
}

__global__ void k_misc(const float* __restrict__ bih, const float* __restrict__ bhh,
                       float* __restrict__ bsum, f16* __restrict__ hbuf) {
  int i = blockIdx.x * blockDim.x + threadIdx.x;
  if (i < 4096) bsum[i] = bih[i] + bhh[i];
  if (i < BSZ * HSZ) hbuf[i] = (f16)0.f;   // zero h ping buffer 0 (ws is poisoned)
}

// ---- phase 1: gx = x @ w_ih^T + (b_ih + b_hh), scattered into [s][wg][b][16] f16
__global__ __launch_bounds__(256) void k_gemm_gx(
    const f16* __restrict__ xh, const f16* __restrict__ wh,
    const float* __restrict__ bsum, f16* __restrict__ gxp)
{
  __shared__ f16 As[128][40];   // +8 pad: 2-way-max LDS bank aliasing (free)
  __shared__ f16 Bs[128][40];
  const int bn = blockIdx.x, bm = blockIdx.y;
  const int tid = threadIdx.x;
  const int wid = tid >> 6, lane = tid & 63;
  const int wy = wid >> 1, wx = wid & 1;       // 2x2 waves, 64x64 each
  const int l15 = lane & 15, lq = lane >> 4;
  const int sr = tid >> 2, sc = (tid & 3) * 8; // staging: 8 f16 per thread x2 rows
  f32x4 acc[4][4] = {};
  const size_t arow = (size_t)bm * 128;
  const size_t brow = (size_t)bn * 128;
  for (int k0 = 0; k0 < ISZ; k0 += 32) {
    __syncthreads();
    *(f16x8*)&As[sr][sc]      = *(const f16x8*)&xh[(arow + sr) * ISZ + k0 + sc];
    *(f16x8*)&As[sr + 64][sc] = *(const f16x8*)&xh[(arow + sr + 64) * ISZ + k0 + sc];
    *(f16x8*)&Bs[sr][sc]      = *(const f16x8*)&wh[(brow + sr) * ISZ + k0 + sc];
    *(f16x8*)&Bs[sr + 64][sc] = *(const f16x8*)&wh[(brow + sr + 64) * ISZ + k0 + sc];
    __syncthreads();
    f16x8 af[4], bf[4];
    #pragma unroll
    for (int t = 0; t < 4; t++) af[t] = *(const f16x8*)&As[wy * 64 + t * 16 + l15][lq * 8];
    #pragma unroll
    for (int t = 0; t < 4; t++) bf[t] = *(const f16x8*)&Bs[wx * 64 + t * 16 + l15][lq * 8];
    #pragma unroll
    for (int mt = 0; mt < 4; mt++)
      #pragma unroll
      for (int nt = 0; nt < 4; nt++)
        acc[mt][nt] = __builtin_amdgcn_mfma_f32_16x16x32_f16(af[mt], bf[nt], acc[mt][nt], 0, 0, 0);
  }
  // epilogue: D row = quad*4+reg (m), col = lane&15 (n). m = b*512+s.
  #pragma unroll
  for (int nt = 0; nt < 4; nt++) {
    const int n = bn * 128 + wx * 64 + nt * 16 + l15;
    const float bs = bsum[n];
    const int cls = n >> 10, j = n & 1023;
    const int wgx = j >> 2;
    const int rr = (j & 3) * 4 + cls;        // r = jj*4 + cls
    #pragma unroll
    for (int mt = 0; mt < 4; mt++) {
      const int m0 = bm * 128 + wy * 64 + mt * 16 + lq * 4;
      #pragma unroll
      for (int r = 0; r < 4; r++) {
        const int m = m0 + r;
        const int b = m >> 9, s = m & 511;
        gxp[(((size_t)s * 256 + wgx) * 64 + b) * 16 + rr] = (f16)(acc[mt][nt][r] + bs);
      }
    }
  }
}

// ---- phase 2: persistent cooperative recurrence --------------------------
// 256 WGs x 512 thr. WG owns hidden j in [4wg,4wg+4) => 16 packed w_hh rows,
// staged to LDS ONCE. c lives in LDS. Only h crosses WGs (f16 ping-pong).
__global__ __launch_bounds__(512) void k_lstm(
    const f16* __restrict__ wp, const f16* __restrict__ gxp,
    f16* __restrict__ hbuf, float* __restrict__ out)
{
  __shared__ f16 wlds[16][1032];       // 33 KB, +8 pad -> 2-way max on ds_read_b128
  __shared__ float glds[2][64][17];    // [khalf][batch][r] partial gates
  __shared__ float c_lds[256];         // [b*4+jj]
  const int wg = blockIdx.x;
  const int tid = threadIdx.x;
  const int wid = tid >> 6, lane = tid & 63;
  const int l15 = lane & 15, lq = lane >> 4;
  const int mt = wid & 3;              // batch tile: rows 16*mt..
  const int kh = wid >> 2;             // K half: 0 or 1 (512 each)
  {
    const f16* wsrc = wp + (size_t)wg * 16 * HSZ;
    for (int i = tid; i < 2048; i += 512) {
      int r = i >> 7, c = (i & 127) * 8;
      *(f16x8*)&wlds[r][c] = *(const f16x8*)&wsrc[r * HSZ + c];
    }
  }
  if (tid < 256) c_lds[tid] = 0.f;
  __syncthreads();
  cg::grid_group grid = cg::this_grid();
  const size_t hseq = (size_t)S_LEN * BSZ * HSZ;
  int p = 0;
  for (int s = 0; s < S_LEN; s++) {
    // prefetch this step's gx slice (contiguous 2 KB) to hide HBM latency
    f16x4 gxv = {};
    if (tid < 256)
      gxv = *(const f16x4*)&gxp[(((size_t)s * 256 + wg) * 64 + (tid >> 2)) * 16 + (tid & 3) * 4];
    const f16* hrow = hbuf + (size_t)p * BSZ * HSZ
                    + (size_t)(mt * 16 + l15) * HSZ + kh * 512 + lq * 8;
    const f16* wrow = &wlds[l15][kh * 512 + lq * 8];
    f32x4 a0 = {}, a1 = {}, a2 = {}, a3 = {};   // 4 accs: break MFMA dep chain
    #pragma unroll
    for (int ks = 0; ks < 16; ks += 4) {
      f16x8 av0 = *(const f16x8*)(hrow + (ks + 0) * 32);
      f16x8 bv0 = *(const f16x8*)(wrow + (ks + 0) * 32);
      f16x8 av1 = *(const f16x8*)(hrow + (ks + 1) * 32);
      f16x8 bv1 = *(const f16x8*)(wrow + (ks + 1) * 32);
      f16x8 av2 = *(const f16x8*)(hrow + (ks + 2) * 32);
      f16x8 bv2 = *(const f16x8*)(wrow + (ks + 2) * 32);
      f16x8 av3 = *(const f16x8*)(hrow + (ks + 3) * 32);
      f16x8 bv3 = *(const f16x8*)(wrow + (ks + 3) * 32);
      a0 = __builtin_amdgcn_mfma_f32_16x16x32_f16(av0, bv0, a0, 0, 0, 0);
      a1 = __builtin_amdgcn_mfma_f32_16x16x32_f16(av1, bv1, a1, 0, 0, 0);
      a2 = __builtin_amdgcn_mfma_f32_16x16x32_f16(av2, bv2, a2, 0, 0, 0);
      a3 = __builtin_amdgcn_mfma_f32_16x16x32_f16(av3, bv3, a3, 0, 0, 0);
    }
    f32x4 accs = (a0 + a1) + (a2 + a3);
    #pragma unroll
    for (int r = 0; r < 4; r++) glds[kh][mt * 16 + lq * 4 + r][l15] = accs[r];
    __syncthreads();
    if (tid < 256) {
      const int b = tid >> 2, jj = tid & 3;
      const float ip = glds[0][b][jj * 4 + 0] + glds[1][b][jj * 4 + 0] + (float)gxv[0];
      const float fp = glds[0][b][jj * 4 + 1] + glds[1][b][jj * 4 + 1] + (float)gxv[1];
      const float gp = glds[0][b][jj * 4 + 2] + glds[1][b][jj * 4 + 2] + (float)gxv[2];
      const float op = glds[0][b][jj * 4 + 3] + glds[1][b][jj * 4 + 3] + (float)gxv[3];
      const float ig = fast_sigmoid(ip);
      const float fg = fast_sigmoid(fp);
      const float gg = fast_tanh(gp);
      const float og = fast_sigmoid(op);
      const float c = fg * c_lds[tid] + ig * gg;
      c_lds[tid] = c;
      const float h = og * fast_tanh(c);
      hbuf[(size_t)(p ^ 1) * BSZ * HSZ + b * HSZ + wg * 4 + jj] = (f16)h;
      out[((size_t)s * BSZ + b) * HSZ + wg * 4 + jj] = h;
      if (s == S_LEN - 1) {
        out[hseq + b * HSZ + wg * 4 + jj] = h;               // h_f
        out[hseq + BSZ * HSZ + b * HSZ + wg * 4 + jj] = c;   // c_f
      }
    }
    __threadfence();   // release h stores device-scope before the barrier
    grid.sync();
    p ^= 1;
  }
}

// ---- launch --------------------------------------------------------------
extern "C" void kernel_launch(void* const* d_in, const int* in_sizes, int n_in,
                              void* d_out, int out_size, void* d_ws, size_t ws_size,
                              hipStream_t stream) {
  const float* x   = (const float*)d_in[0];
  const float* wih = (const float*)d_in[1];
  const float* whh = (const float*)d_in[2];
  const float* bih = (const float*)d_in[3];
  const float* bhh = (const float*)d_in[4];
  float* out = (float*)d_out;
  char* ws = (char*)d_ws;
  // workspace layout (bytes)
  f16*   xh    = (f16*)(ws + 0);           // 33,554,432  x as f16
  f16*   wih_h = (f16*)(ws + 33554432);    //  4,194,304  w_ih as f16
  f16*   wp    = (f16*)(ws + 37748736);    //  8,388,608  packed w_hh f16
  float* bsum  = (float*)(ws + 46137344);  //     16,384  b_ih+b_hh
  f16*   hbuf  = (f16*)(ws + 46153728);    //    262,144  h ping-pong f16
  f16*   gxp   = (f16*)(ws + 46415872);    // 268,435,456 gx f16 [s][wg][b][16]
  // total 314,851,328 B

  k_cvt<<<16384, 256, 0, stream>>>(x, xh, (BSZ * S_LEN * ISZ) / 4);
  k_cvt<<<2048, 256, 0, stream>>>(wih, wih_h, (4 * HSZ * ISZ) / 4);
  k_pack_whh<<<4096, 256, 0, stream>>>(whh, wp);
  k_misc<<<256, 256, 0, stream>>>(bih, bhh, bsum, hbuf);
  dim3 g1(32, 256);   // (N/128, M/128)
  k_gemm_gx<<<g1, 256, 0, stream>>>(xh, wih_h, bsum, gxp);
  void* args[] = { (void*)&wp, (void*)&gxp, (void*)&hbuf, (void*)&out };
  hipLaunchCooperativeKernel((void*)k_lstm, dim3(256), dim3(512), args, 0, stream);
}

// Round 2
// 6715.726 us; speedup vs baseline: 5.9624x; 5.9624x over previous
//
#include <hip/hip_runtime.h>

typedef _Float16 f16;
typedef _Float16 f16x4 __attribute__((ext_vector_type(4)));
typedef _Float16 f16x8 __attribute__((ext_vector_type(8)));
typedef float f32x4 __attribute__((ext_vector_type(4)));

#define S_LEN 512
#define BSZ 64
#define ISZ 512
#define HSZ 1024

__device__ __forceinline__ float fast_sigmoid(float x) {
  return 1.f / (1.f + __expf(-x));
}
__device__ __forceinline__ float fast_tanh(float x) {
  float t = __expf(-2.f * fabsf(x));
  float r = (1.f - t) / (1.f + t);
  return copysignf(r, x);
}

// coherent (cross-XCD) 16B load as two relaxed agent-scope 8B atomic loads.
// Relaxed agent atomics emit sc1 (bypass the non-coherent per-XCD L2, served
// by Infinity Cache) with NO cache-maintenance fences and full pipelining.
__device__ __forceinline__ f16x8 ld_h16(const f16* p) {
  unsigned long long lo = __hip_atomic_load((unsigned long long*)p,
                                            __ATOMIC_RELAXED, __HIP_MEMORY_SCOPE_AGENT);
  unsigned long long hi = __hip_atomic_load((unsigned long long*)p + 1,
                                            __ATOMIC_RELAXED, __HIP_MEMORY_SCOPE_AGENT);
  union { unsigned long long q[2]; f16x8 v; } u;
  u.q[0] = lo; u.q[1] = hi;
  return u.v;
}

// ---- setup kernels -------------------------------------------------------
__global__ void k_cvt(const float* __restrict__ src, f16* __restrict__ dst, int n4) {
  int i = blockIdx.x * blockDim.x + threadIdx.x;
  if (i < n4) {
    float4 v = ((const float4*)src)[i];
    f16x4 h = { (f16)v.x, (f16)v.y, (f16)v.z, (f16)v.w };
    ((f16x4*)dst)[i] = h;
  }
}

__global__ void k_pack_whh(const float* __restrict__ whh, f16* __restrict__ wp) {
  int i = blockIdx.x * blockDim.x + threadIdx.x;
  int idx4 = i * 4;
  int k  = idx4 & (HSZ - 1);
  int rg = idx4 >> 10;
  int wg = rg >> 4, r = rg & 15;
  int jj = r >> 2, cls = r & 3;
  int srow = cls * HSZ + wg * 4 + jj;
  float4 v = *(const float4*)&whh[(size_t)srow * HSZ + k];
  f16x4 h = { (f16)v.x, (f16)v.y, (f16)v.z, (f16)v.w };
  *(f16x4*)&wp[(size_t)rg * HSZ + k] = h;
}

__global__ void k_misc(const float* __restrict__ bih, const float* __restrict__ bhh,
                       float* __restrict__ bsum, f16* __restrict__ hbuf,
                       int* __restrict__ bar) {
  int i = blockIdx.x * blockDim.x + threadIdx.x;
  if (i < 4096) bsum[i] = bih[i] + bhh[i];
  if (i < BSZ * HSZ) hbuf[i] = (f16)0.f;   // zero h ping buffer 0 (ws is poisoned)
  if (i < 1024) bar[i] = 0;                // barrier counters
}

// ---- phase 1: gx = x @ w_ih^T + (b_ih + b_hh) -> [s][wg][b][16] f16 ------
__global__ __launch_bounds__(256) void k_gemm_gx(
    const f16* __restrict__ xh, const f16* __restrict__ wh,
    const float* __restrict__ bsum, f16* __restrict__ gxp)
{
  __shared__ f16 As[128][40];
  __shared__ f16 Bs[128][40];
  const int bn = blockIdx.x, bm = blockIdx.y;
  const int tid = threadIdx.x;
  const int wid = tid >> 6, lane = tid & 63;
  const int wy = wid >> 1, wx = wid & 1;
  const int l15 = lane & 15, lq = lane >> 4;
  const int sr = tid >> 2, sc = (tid & 3) * 8;
  f32x4 acc[4][4] = {};
  const size_t arow = (size_t)bm * 128;
  const size_t brow = (size_t)bn * 128;
  for (int k0 = 0; k0 < ISZ; k0 += 32) {
    __syncthreads();
    *(f16x8*)&As[sr][sc]      = *(const f16x8*)&xh[(arow + sr) * ISZ + k0 + sc];
    *(f16x8*)&As[sr + 64][sc] = *(const f16x8*)&xh[(arow + sr + 64) * ISZ + k0 + sc];
    *(f16x8*)&Bs[sr][sc]      = *(const f16x8*)&wh[(brow + sr) * ISZ + k0 + sc];
    *(f16x8*)&Bs[sr + 64][sc] = *(const f16x8*)&wh[(brow + sr + 64) * ISZ + k0 + sc];
    __syncthreads();
    f16x8 af[4], bf[4];
    #pragma unroll
    for (int t = 0; t < 4; t++) af[t] = *(const f16x8*)&As[wy * 64 + t * 16 + l15][lq * 8];
    #pragma unroll
    for (int t = 0; t < 4; t++) bf[t] = *(const f16x8*)&Bs[wx * 64 + t * 16 + l15][lq * 8];
    #pragma unroll
    for (int mt = 0; mt < 4; mt++)
      #pragma unroll
      for (int nt = 0; nt < 4; nt++)
        acc[mt][nt] = __builtin_amdgcn_mfma_f32_16x16x32_f16(af[mt], bf[nt], acc[mt][nt], 0, 0, 0);
  }
  #pragma unroll
  for (int nt = 0; nt < 4; nt++) {
    const int n = bn * 128 + wx * 64 + nt * 16 + l15;
    const float bs = bsum[n];
    const int cls = n >> 10, j = n & 1023;
    const int wgx = j >> 2;
    const int rr = (j & 3) * 4 + cls;
    #pragma unroll
    for (int mt = 0; mt < 4; mt++) {
      const int m0 = bm * 128 + wy * 64 + mt * 16 + lq * 4;
      #pragma unroll
      for (int r = 0; r < 4; r++) {
        const int m = m0 + r;
        const int b = m >> 9, s = m & 511;
        gxp[(((size_t)s * 256 + wgx) * 64 + b) * 16 + rr] = (f16)(acc[mt][nt][r] + bs);
      }
    }
  }
}

// ---- phase 2: persistent recurrence, custom fence-free barrier -----------
// 256 WGs x 512 thr (1/CU). WG owns hidden j in [4wg,4wg+4) (16 packed w_hh
// rows, in LDS once). c in LDS. Cross-WG traffic = h only, via relaxed
// agent-scope atomics (sc1, Infinity-Cache coherent, no L2 flushes).
__global__ __launch_bounds__(512) void k_lstm(
    const f16* __restrict__ wp, const f16* __restrict__ gxp,
    f16* __restrict__ hbuf, int* __restrict__ bar, float* __restrict__ out)
{
  __shared__ f16 wlds[16][1032];
  __shared__ float glds[2][64][17];
  __shared__ float c_lds[256];
  __shared__ alignas(16) f16 harr[256];
  const int wg = blockIdx.x;
  const int tid = threadIdx.x;
  const int lane = tid & 63;
  const int wid = tid >> 6;
  const int l15 = lane & 15, lq = lane >> 4;
  const int mt = wid & 3;              // batch tile
  const int kh = wid >> 2;             // K half
  int* barg = &bar[(wg >> 4) * 32];    // 16 group counters, 128B apart
  int* root = &bar[512];
  {
    const f16* wsrc = wp + (size_t)wg * 16 * HSZ;
    for (int i = tid; i < 2048; i += 512) {
      int r = i >> 7, c = (i & 127) * 8;
      *(f16x8*)&wlds[r][c] = *(const f16x8*)&wsrc[r * HSZ + c];
    }
  }
  if (tid < 256) c_lds[tid] = 0.f;
  __syncthreads();
  const size_t hseq = (size_t)S_LEN * BSZ * HSZ;
  int p = 0;
  for (int s = 0; s < S_LEN; s++) {
    // prefetch this step's gx slice (normal cached load, overlaps the spin)
    f16x4 gxv = {};
    if (tid < 256)
      gxv = *(const f16x4*)&gxp[((size_t)s * 256 + wg) * 1024 + tid * 4];
    if (s > 0) {
      if (tid == 0) {
        while (__hip_atomic_load(root, __ATOMIC_RELAXED, __HIP_MEMORY_SCOPE_AGENT) < 16 * s)
          __builtin_amdgcn_s_sleep(2);
      }
      __syncthreads();   // releases all waves once the barrier opened
    }
    const f16* hrow = hbuf + (size_t)p * BSZ * HSZ
                    + (size_t)(mt * 16 + l15) * HSZ + kh * 512 + lq * 8;
    const f16* wrow = &wlds[l15][kh * 512 + lq * 8];
    f32x4 a0 = {}, a1 = {}, a2 = {}, a3 = {};
    #pragma unroll
    for (int ks = 0; ks < 16; ks += 4) {
      f16x8 av0 = ld_h16(hrow + (ks + 0) * 32);
      f16x8 bv0 = *(const f16x8*)(wrow + (ks + 0) * 32);
      f16x8 av1 = ld_h16(hrow + (ks + 1) * 32);
      f16x8 bv1 = *(const f16x8*)(wrow + (ks + 1) * 32);
      f16x8 av2 = ld_h16(hrow + (ks + 2) * 32);
      f16x8 bv2 = *(const f16x8*)(wrow + (ks + 2) * 32);
      f16x8 av3 = ld_h16(hrow + (ks + 3) * 32);
      f16x8 bv3 = *(const f16x8*)(wrow + (ks + 3) * 32);
      a0 = __builtin_amdgcn_mfma_f32_16x16x32_f16(av0, bv0, a0, 0, 0, 0);
      a1 = __builtin_amdgcn_mfma_f32_16x16x32_f16(av1, bv1, a1, 0, 0, 0);
      a2 = __builtin_amdgcn_mfma_f32_16x16x32_f16(av2, bv2, a2, 0, 0, 0);
      a3 = __builtin_amdgcn_mfma_f32_16x16x32_f16(av3, bv3, a3, 0, 0, 0);
    }
    f32x4 accs = (a0 + a1) + (a2 + a3);
    #pragma unroll
    for (int r = 0; r < 4; r++) glds[kh][mt * 16 + lq * 4 + r][l15] = accs[r];
    __syncthreads();
    if (tid < 256) {
      const int b = tid >> 2, jj = tid & 3;
      const float ip = glds[0][b][jj * 4 + 0] + glds[1][b][jj * 4 + 0] + (float)gxv[0];
      const float fp = glds[0][b][jj * 4 + 1] + glds[1][b][jj * 4 + 1] + (float)gxv[1];
      const float gp = glds[0][b][jj * 4 + 2] + glds[1][b][jj * 4 + 2] + (float)gxv[2];
      const float op = glds[0][b][jj * 4 + 3] + glds[1][b][jj * 4 + 3] + (float)gxv[3];
      const float ig = fast_sigmoid(ip);
      const float fg = fast_sigmoid(fp);
      const float gg = fast_tanh(gp);
      const float og = fast_sigmoid(op);
      const float c = fg * c_lds[tid] + ig * gg;
      c_lds[tid] = c;
      const float h = og * fast_tanh(c);
      harr[tid] = (f16)h;
      out[((size_t)s * BSZ + b) * HSZ + wg * 4 + jj] = h;   // normal cached store
      if (s == S_LEN - 1) {
        out[hseq + b * HSZ + wg * 4 + jj] = h;               // h_f
        out[hseq + BSZ * HSZ + b * HSZ + wg * 4 + jj] = c;   // c_f
      }
    }
    __syncthreads();   // harr ready
    if (tid < 64) {    // coherent publish: one 8B agent atomic store per batch
      unsigned long long q;
      __builtin_memcpy(&q, &harr[tid * 4], 8);
      __hip_atomic_store((unsigned long long*)&hbuf[(size_t)(p ^ 1) * BSZ * HSZ + tid * HSZ + wg * 4],
                         q, __ATOMIC_RELAXED, __HIP_MEMORY_SCOPE_AGENT);
    }
    __syncthreads();   // vmcnt(0) drain: h stores ack'd at coherence point
    if (tid == 0) {
      __builtin_amdgcn_s_waitcnt(0);   // belt+suspenders before arrive
      int old = __hip_atomic_fetch_add(barg, 1, __ATOMIC_RELAXED, __HIP_MEMORY_SCOPE_AGENT);
      if ((old & 15) == 15)
        __hip_atomic_fetch_add(root, 1, __ATOMIC_RELAXED, __HIP_MEMORY_SCOPE_AGENT);
    }
    p ^= 1;
  }
}

// ---- launch --------------------------------------------------------------
extern "C" void kernel_launch(void* const* d_in, const int* in_sizes, int n_in,
                              void* d_out, int out_size, void* d_ws, size_t ws_size,
                              hipStream_t stream) {
  const float* x   = (const float*)d_in[0];
  const float* wih = (const float*)d_in[1];
  const float* whh = (const float*)d_in[2];
  const float* bih = (const float*)d_in[3];
  const float* bhh = (const float*)d_in[4];
  float* out = (float*)d_out;
  char* ws = (char*)d_ws;
  f16*   xh    = (f16*)(ws + 0);           // 33,554,432
  f16*   wih_h = (f16*)(ws + 33554432);    //  4,194,304
  f16*   wp    = (f16*)(ws + 37748736);    //  8,388,608
  float* bsum  = (float*)(ws + 46137344);  //     16,384
  f16*   hbuf  = (f16*)(ws + 46153728);    //    262,144
  f16*   gxp   = (f16*)(ws + 46415872);    // 268,435,456
  int*   bar   = (int*)(ws + 314851328);   //      4,096
  // total 314,855,424 B

  k_cvt<<<16384, 256, 0, stream>>>(x, xh, (BSZ * S_LEN * ISZ) / 4);
  k_cvt<<<2048, 256, 0, stream>>>(wih, wih_h, (4 * HSZ * ISZ) / 4);
  k_pack_whh<<<4096, 256, 0, stream>>>(whh, wp);
  k_misc<<<256, 256, 0, stream>>>(bih, bhh, bsum, hbuf, bar);
  dim3 g1(32, 256);
  k_gemm_gx<<<g1, 256, 0, stream>>>(xh, wih_h, bsum, gxp);
  void* args[] = { (void*)&wp, (void*)&gxp, (void*)&hbuf, (void*)&bar, (void*)&out };
  hipLaunchCooperativeKernel((void*)k_lstm, dim3(256), dim3(512), args, 0, stream);
}

// Round 3
// 5194.331 us; speedup vs baseline: 7.7088x; 1.2929x over previous
//
#include <hip/hip_runtime.h>

typedef _Float16 f16;
typedef _Float16 f16x4 __attribute__((ext_vector_type(4)));
typedef _Float16 f16x8 __attribute__((ext_vector_type(8)));
typedef float f32x4 __attribute__((ext_vector_type(4)));

#define S_LEN 512
#define BSZ 64
#define ISZ 512
#define HSZ 1024

__device__ __forceinline__ float fast_sigmoid(float x) {
  return 1.f / (1.f + __expf(-x));
}
__device__ __forceinline__ float fast_tanh(float x) {
  float t = __expf(-2.f * fabsf(x));
  float r = (1.f - t) / (1.f + t);
  return copysignf(r, x);
}

// 16B device-coherent load (sc1: served at the coherence point / Infinity
// Cache, bypasses the non-coherent per-XCD L2). NOT atomic -- we only need
// the scope bit, so these pipeline like normal loads.
template<int OFF>
__device__ __forceinline__ void ldg16_sc1(f16x8& d, const f16* p) {
  asm volatile("global_load_dwordx4 %0, %1, off offset:%2 sc1"
               : "=v"(d) : "v"(p), "i"(OFF));
}

// ---- setup kernels -------------------------------------------------------
__global__ void k_cvt(const float* __restrict__ src, f16* __restrict__ dst, int n4) {
  int i = blockIdx.x * blockDim.x + threadIdx.x;
  if (i < n4) {
    float4 v = ((const float4*)src)[i];
    f16x4 h = { (f16)v.x, (f16)v.y, (f16)v.z, (f16)v.w };
    ((f16x4*)dst)[i] = h;
  }
}

__global__ void k_pack_whh(const float* __restrict__ whh, f16* __restrict__ wp) {
  int i = blockIdx.x * blockDim.x + threadIdx.x;
  int idx4 = i * 4;
  int k  = idx4 & (HSZ - 1);
  int rg = idx4 >> 10;
  int wg = rg >> 4, r = rg & 15;
  int jj = r >> 2, cls = r & 3;
  int srow = cls * HSZ + wg * 4 + jj;
  float4 v = *(const float4*)&whh[(size_t)srow * HSZ + k];
  f16x4 h = { (f16)v.x, (f16)v.y, (f16)v.z, (f16)v.w };
  *(f16x4*)&wp[(size_t)rg * HSZ + k] = h;
}

__global__ void k_misc(const float* __restrict__ bih, const float* __restrict__ bhh,
                       float* __restrict__ bsum, f16* __restrict__ hbuf,
                       int* __restrict__ bar) {
  int i = blockIdx.x * blockDim.x + threadIdx.x;
  if (i < 4096) bsum[i] = bih[i] + bhh[i];
  if (i < BSZ * HSZ) hbuf[i] = (f16)0.f;   // zero h ping buffer 0 (ws is poisoned)
  if (i < 1024) bar[i] = 0;                // barrier counters
}

// ---- phase 1: gx = x @ w_ih^T + (b_ih + b_hh) -> [s][wgx][b][16] f16 -----
__global__ __launch_bounds__(256) void k_gemm_gx(
    const f16* __restrict__ xh, const f16* __restrict__ wh,
    const float* __restrict__ bsum, f16* __restrict__ gxp)
{
  __shared__ f16 As[128][40];
  __shared__ f16 Bs[128][40];
  const int bn = blockIdx.x, bm = blockIdx.y;
  const int tid = threadIdx.x;
  const int wid = tid >> 6, lane = tid & 63;
  const int wy = wid >> 1, wx = wid & 1;
  const int l15 = lane & 15, lq = lane >> 4;
  const int sr = tid >> 2, sc = (tid & 3) * 8;
  f32x4 acc[4][4] = {};
  const size_t arow = (size_t)bm * 128;
  const size_t brow = (size_t)bn * 128;
  for (int k0 = 0; k0 < ISZ; k0 += 32) {
    __syncthreads();
    *(f16x8*)&As[sr][sc]      = *(const f16x8*)&xh[(arow + sr) * ISZ + k0 + sc];
    *(f16x8*)&As[sr + 64][sc] = *(const f16x8*)&xh[(arow + sr + 64) * ISZ + k0 + sc];
    *(f16x8*)&Bs[sr][sc]      = *(const f16x8*)&wh[(brow + sr) * ISZ + k0 + sc];
    *(f16x8*)&Bs[sr + 64][sc] = *(const f16x8*)&wh[(brow + sr + 64) * ISZ + k0 + sc];
    __syncthreads();
    f16x8 af[4], bf[4];
    #pragma unroll
    for (int t = 0; t < 4; t++) af[t] = *(const f16x8*)&As[wy * 64 + t * 16 + l15][lq * 8];
    #pragma unroll
    for (int t = 0; t < 4; t++) bf[t] = *(const f16x8*)&Bs[wx * 64 + t * 16 + l15][lq * 8];
    #pragma unroll
    for (int mt = 0; mt < 4; mt++)
      #pragma unroll
      for (int nt = 0; nt < 4; nt++)
        acc[mt][nt] = __builtin_amdgcn_mfma_f32_16x16x32_f16(af[mt], bf[nt], acc[mt][nt], 0, 0, 0);
  }
  #pragma unroll
  for (int nt = 0; nt < 4; nt++) {
    const int n = bn * 128 + wx * 64 + nt * 16 + l15;
    const float bs = bsum[n];
    const int cls = n >> 10, j = n & 1023;
    const int wgx = j >> 2;
    const int rr = (j & 3) * 4 + cls;
    #pragma unroll
    for (int mt = 0; mt < 4; mt++) {
      const int m0 = bm * 128 + wy * 64 + mt * 16 + lq * 4;
      #pragma unroll
      for (int r = 0; r < 4; r++) {
        const int m = m0 + r;
        const int b = m >> 9, s = m & 511;
        gxp[(((size_t)s * 256 + wgx) * 64 + b) * 16 + rr] = (f16)(acc[mt][nt][r] + bs);
      }
    }
  }
}

// ---- phase 2: persistent recurrence --------------------------------------
// 256 WGs x 512 thr, 1/CU (LDS pad enforces). WG `wg` owns j-block
// wgx=(wg&7)<<5|(wg>>3) (XCD-aware: the 4 WGs sharing a 64B out-line sit on
// one XCD under RR dispatch -> full-line writebacks). Weights live in VGPRs.
// h crosses WGs via raw sc1 (device-coherent) loads/stores; custom fence-free
// fan-in barrier.
__global__ __launch_bounds__(512, 2) void k_lstm(
    const f16* __restrict__ wp, const f16* __restrict__ gxp,
    f16* __restrict__ hbuf, int* __restrict__ bar, float* __restrict__ out)
{
  __shared__ float glds[2][64][17];
  __shared__ float c_lds[256];
  __shared__ f16 lds_pad[45056];   // 88KB -> 2 WGs can't co-reside on a CU
  const int wg = blockIdx.x;
  const int wgx = ((wg & 7) << 5) | (wg >> 3);
  const int tid = threadIdx.x;
  const int lane = tid & 63;
  const int wid = tid >> 6;
  const int l15 = lane & 15, lq = lane >> 4;
  const int mt = wid & 3;              // batch tile
  const int kh = wid >> 2;             // K half
  int* barg = &bar[(wg >> 4) * 32];    // 16 group counters, 128B apart
  int* root = &bar[512];
  lds_pad[tid] = (f16)0.f;             // keep the pad alive
  // B-fragments (w_hh) resident in registers for the whole sequence
  f16x8 wv[16];
  {
    const f16* wsrc = wp + (size_t)wgx * 16 * HSZ + (size_t)l15 * HSZ + kh * 512 + lq * 8;
    #pragma unroll
    for (int t = 0; t < 16; t++) wv[t] = *(const f16x8*)(wsrc + t * 32);
  }
  if (tid < 256) c_lds[tid] = 0.f;
  __syncthreads();
  const size_t hseq = (size_t)S_LEN * BSZ * HSZ;
  int p = 0;
  for (int s = 0; s < S_LEN; s++) {
    // prefetch this step's gx slice (normal cached load, in flight during spin)
    f16x4 gxv = {};
    if (tid < 256)
      gxv = *(const f16x4*)&gxp[((size_t)s * 256 + wgx) * 1024 + tid * 4];
    if (s > 0) {
      if (tid == 0) {
        while (__hip_atomic_load(root, __ATOMIC_RELAXED, __HIP_MEMORY_SCOPE_AGENT) < 16 * s)
          __builtin_amdgcn_s_sleep(2);
      }
      __syncthreads();
    }
    const f16* hrow = hbuf + (size_t)p * BSZ * HSZ
                    + (size_t)(mt * 16 + l15) * HSZ + kh * 512 + lq * 8;
    f16x8 hv0, hv1, hv2, hv3, hv4, hv5, hv6, hv7;
    f16x8 hv8, hv9, hv10, hv11, hv12, hv13, hv14, hv15;
    ldg16_sc1<0>(hv0, hrow);    ldg16_sc1<64>(hv1, hrow);
    ldg16_sc1<128>(hv2, hrow);  ldg16_sc1<192>(hv3, hrow);
    ldg16_sc1<256>(hv4, hrow);  ldg16_sc1<320>(hv5, hrow);
    ldg16_sc1<384>(hv6, hrow);  ldg16_sc1<448>(hv7, hrow);
    ldg16_sc1<512>(hv8, hrow);  ldg16_sc1<576>(hv9, hrow);
    ldg16_sc1<640>(hv10, hrow); ldg16_sc1<704>(hv11, hrow);
    ldg16_sc1<768>(hv12, hrow); ldg16_sc1<832>(hv13, hrow);
    ldg16_sc1<896>(hv14, hrow); ldg16_sc1<960>(hv15, hrow);
    asm volatile("s_waitcnt vmcnt(0)"
      : "+v"(hv0), "+v"(hv1), "+v"(hv2), "+v"(hv3),
        "+v"(hv4), "+v"(hv5), "+v"(hv6), "+v"(hv7),
        "+v"(hv8), "+v"(hv9), "+v"(hv10), "+v"(hv11),
        "+v"(hv12), "+v"(hv13), "+v"(hv14), "+v"(hv15)
      :: "memory");
    f32x4 a0 = {}, a1 = {}, a2 = {}, a3 = {};
    a0 = __builtin_amdgcn_mfma_f32_16x16x32_f16(hv0,  wv[0],  a0, 0, 0, 0);
    a1 = __builtin_amdgcn_mfma_f32_16x16x32_f16(hv1,  wv[1],  a1, 0, 0, 0);
    a2 = __builtin_amdgcn_mfma_f32_16x16x32_f16(hv2,  wv[2],  a2, 0, 0, 0);
    a3 = __builtin_amdgcn_mfma_f32_16x16x32_f16(hv3,  wv[3],  a3, 0, 0, 0);
    a0 = __builtin_amdgcn_mfma_f32_16x16x32_f16(hv4,  wv[4],  a0, 0, 0, 0);
    a1 = __builtin_amdgcn_mfma_f32_16x16x32_f16(hv5,  wv[5],  a1, 0, 0, 0);
    a2 = __builtin_amdgcn_mfma_f32_16x16x32_f16(hv6,  wv[6],  a2, 0, 0, 0);
    a3 = __builtin_amdgcn_mfma_f32_16x16x32_f16(hv7,  wv[7],  a3, 0, 0, 0);
    a0 = __builtin_amdgcn_mfma_f32_16x16x32_f16(hv8,  wv[8],  a0, 0, 0, 0);
    a1 = __builtin_amdgcn_mfma_f32_16x16x32_f16(hv9,  wv[9],  a1, 0, 0, 0);
    a2 = __builtin_amdgcn_mfma_f32_16x16x32_f16(hv10, wv[10], a2, 0, 0, 0);
    a3 = __builtin_amdgcn_mfma_f32_16x16x32_f16(hv11, wv[11], a3, 0, 0, 0);
    a0 = __builtin_amdgcn_mfma_f32_16x16x32_f16(hv12, wv[12], a0, 0, 0, 0);
    a1 = __builtin_amdgcn_mfma_f32_16x16x32_f16(hv13, wv[13], a1, 0, 0, 0);
    a2 = __builtin_amdgcn_mfma_f32_16x16x32_f16(hv14, wv[14], a2, 0, 0, 0);
    a3 = __builtin_amdgcn_mfma_f32_16x16x32_f16(hv15, wv[15], a3, 0, 0, 0);
    f32x4 accs = (a0 + a1) + (a2 + a3);
    #pragma unroll
    for (int r = 0; r < 4; r++) glds[kh][mt * 16 + lq * 4 + r][l15] = accs[r];
    __syncthreads();
    if (tid < 256) {
      const int b = tid >> 2, jj = tid & 3;
      const float ip = glds[0][b][jj * 4 + 0] + glds[1][b][jj * 4 + 0] + (float)gxv[0];
      const float fp = glds[0][b][jj * 4 + 1] + glds[1][b][jj * 4 + 1] + (float)gxv[1];
      const float gp = glds[0][b][jj * 4 + 2] + glds[1][b][jj * 4 + 2] + (float)gxv[2];
      const float op = glds[0][b][jj * 4 + 3] + glds[1][b][jj * 4 + 3] + (float)gxv[3];
      const float ig = fast_sigmoid(ip);
      const float fg = fast_sigmoid(fp);
      const float gg = fast_tanh(gp);
      const float og = fast_sigmoid(op);
      const float c = fg * c_lds[tid] + ig * gg;
      c_lds[tid] = c;
      const float h = og * fast_tanh(c);
      out[((size_t)s * BSZ + b) * HSZ + wgx * 4 + jj] = h;   // normal cached store
      // publish own h: 2B device-coherent store
      f16 hf = (f16)h;
      unsigned hb;
      { unsigned short u = __builtin_bit_cast(unsigned short, hf); hb = u; }
      asm volatile("global_store_short %0, %1, off sc1"
                   :: "v"(&hbuf[(size_t)(p ^ 1) * BSZ * HSZ + (size_t)b * HSZ + wgx * 4 + jj]),
                      "v"(hb) : "memory");
      if (s == S_LEN - 1) {
        out[hseq + b * HSZ + wgx * 4 + jj] = h;               // h_f
        out[hseq + BSZ * HSZ + b * HSZ + wgx * 4 + jj] = c;   // c_f
      }
      if (lane == 0) {   // 4 arrivals/WG (waves 0-3), each after its own drain
        asm volatile("s_waitcnt vmcnt(0)" ::: "memory");
        int old = __hip_atomic_fetch_add(barg, 1, __ATOMIC_RELAXED, __HIP_MEMORY_SCOPE_AGENT);
        if ((old & 63) == 63)
          __hip_atomic_fetch_add(root, 1, __ATOMIC_RELAXED, __HIP_MEMORY_SCOPE_AGENT);
      }
    }
    p ^= 1;
  }
}

// ---- launch --------------------------------------------------------------
extern "C" void kernel_launch(void* const* d_in, const int* in_sizes, int n_in,
                              void* d_out, int out_size, void* d_ws, size_t ws_size,
                              hipStream_t stream) {
  const float* x   = (const float*)d_in[0];
  const float* wih = (const float*)d_in[1];
  const float* whh = (const float*)d_in[2];
  const float* bih = (const float*)d_in[3];
  const float* bhh = (const float*)d_in[4];
  float* out = (float*)d_out;
  char* ws = (char*)d_ws;
  f16*   xh    = (f16*)(ws + 0);           // 33,554,432
  f16*   wih_h = (f16*)(ws + 33554432);    //  4,194,304
  f16*   wp    = (f16*)(ws + 37748736);    //  8,388,608
  float* bsum  = (float*)(ws + 46137344);  //     16,384
  f16*   hbuf  = (f16*)(ws + 46153728);    //    262,144
  f16*   gxp   = (f16*)(ws + 46415872);    // 268,435,456
  int*   bar   = (int*)(ws + 314851328);   //      4,096
  // total 314,855,424 B

  k_cvt<<<16384, 256, 0, stream>>>(x, xh, (BSZ * S_LEN * ISZ) / 4);
  k_cvt<<<2048, 256, 0, stream>>>(wih, wih_h, (4 * HSZ * ISZ) / 4);
  k_pack_whh<<<4096, 256, 0, stream>>>(whh, wp);
  k_misc<<<256, 256, 0, stream>>>(bih, bhh, bsum, hbuf, bar);
  dim3 g1(32, 256);
  k_gemm_gx<<<g1, 256, 0, stream>>>(xh, wih_h, bsum, gxp);
  void* args[] = { (void*)&wp, (void*)&gxp, (void*)&hbuf, (void*)&bar, (void*)&out };
  hipLaunchCooperativeKernel((void*)k_lstm, dim3(256), dim3(512), args, 0, stream);
}